// Round 5
// baseline (346.640 us; speedup 1.0000x reference)
//
#include <hip/hip_runtime.h>
#include <math.h>

#define HW 36864
#define CC 192

typedef __attribute__((ext_vector_type(4))) float f32x4;
typedef __attribute__((ext_vector_type(8))) short bf16x8;

__device__ __forceinline__ float bf2f(unsigned short u) {
    return __uint_as_float(((unsigned int)u) << 16);
}
__device__ __forceinline__ unsigned short f2bf(float f) {
    unsigned int u = __float_as_uint(f);
    unsigned int r = (u + 0x7fffu + ((u >> 16) & 1u)) >> 16;
    return (unsigned short)r;
}

// ---------------------------------------------------------------------------
// Tile transpose: src [b][192 ch][HW] (f32 or bf16) -> dst bf16 [b][HW][192].
// 64ch x 64n tiles through LDS. Reads coalesced (128B row segments), writes
// coalesced (8 rows x 128B contiguous per instr). LDS stride 33 dwords.
// Grid: (HW/64, 3, batch), 256 threads.
// ---------------------------------------------------------------------------
template<bool INF32>
__global__ __launch_bounds__(256) void xpose_kernel(
    const void* __restrict__ src, unsigned short* __restrict__ dst,
    long srcBatchStride)
{
    const int n0  = blockIdx.x * 64;
    const int ch0 = blockIdx.y * 64;
    const int b   = blockIdx.z;
    const int tid = threadIdx.x;
    const int chp = tid >> 3;   // channel pair 0..31
    const int nq  = tid & 7;    // n-chunk of 8

    __shared__ unsigned int T[64 * 33];

    const long rbase = (long)b * srcBatchStride + (long)(ch0 + 2 * chp) * HW + n0 + nq * 8;
    unsigned int pk[8];
    if (INF32) {
        const float* s0 = (const float*)src + rbase;
        float4 a0 = *(const float4*)(s0);
        float4 a1 = *(const float4*)(s0 + 4);
        float4 b0 = *(const float4*)(s0 + HW);
        float4 b1 = *(const float4*)(s0 + HW + 4);
        float lo[8] = {a0.x, a0.y, a0.z, a0.w, a1.x, a1.y, a1.z, a1.w};
        float hi[8] = {b0.x, b0.y, b0.z, b0.w, b1.x, b1.y, b1.z, b1.w};
#pragma unroll
        for (int j = 0; j < 8; ++j)
            pk[j] = (unsigned int)f2bf(lo[j]) | ((unsigned int)f2bf(hi[j]) << 16);
    } else {
        const unsigned short* s0 = (const unsigned short*)src + rbase;
        int4 r0 = *(const int4*)(s0);
        int4 r1 = *(const int4*)(s0 + HW);
        const unsigned short* u0 = (const unsigned short*)&r0;
        const unsigned short* u1 = (const unsigned short*)&r1;
#pragma unroll
        for (int j = 0; j < 8; ++j)
            pk[j] = (unsigned int)u0[j] | ((unsigned int)u1[j] << 16);
    }
#pragma unroll
    for (int j = 0; j < 8; ++j)
        T[(nq * 8 + j) * 33 + chp] = pk[j];
    __syncthreads();

    // readout: 512 slots = 64 n-rows x 8 segs (16B)
#pragma unroll
    for (int it = 0; it < 2; ++it) {
        const int slot = it * 256 + tid;
        const int n = slot >> 3, seg = slot & 7;
        uint4 v = *(const uint4*)&T[n * 33 + seg * 4];
        *(uint4*)(dst + ((long)b * HW + n0 + n) * 192 + ch0 + seg * 8) = v;
    }
}

// ---------------------------------------------------------------------------
// LDS-free streaming GEMM: Out[b][m][n] = sum_k A[b][m][k] * XT[b][n][k]
// A: bf16 [M][192] k-contig (L2-hot, register-persistent: 48 rows/wave).
// XT: bf16 [HW][192] k-contig -> direct B-frag loads (16 full lines/instr).
// Block = 4 waves = 192 m x 48 n. No LDS, no barriers.
// Grid: (HW/48, batch, M/192).
// ---------------------------------------------------------------------------
template<bool OUTBF>
__global__ __launch_bounds__(256, 4) void gemm_nols(
    const unsigned short* __restrict__ A,
    const unsigned short* __restrict__ XT,
    void* __restrict__ Outv,
    long aBatchStride, long oBatchStride)
{
    const int n0 = blockIdx.x * 48;
    const int b  = blockIdx.y;
    const int mbase = blockIdx.z * 192 + (int)(threadIdx.x >> 6) * 48;
    const int lane = threadIdx.x & 63;
    const int ml = lane & 15, qk = lane >> 4;

    // A fragments: 48 rows x 192 k per wave, loaded once (L2-hot)
    const unsigned short* Ab = A + (long)b * aBatchStride;
    bf16x8 afr[3][6];
#pragma unroll
    for (int f = 0; f < 3; ++f) {
        const unsigned short* row = Ab + (long)(mbase + f * 16 + ml) * 192 + qk * 8;
#pragma unroll
        for (int kk = 0; kk < 6; ++kk)
            afr[f][kk] = *(const bf16x8*)(row + kk * 32);
    }

    const unsigned short* Xb = XT + ((long)b * HW + n0) * 192;

    f32x4 acc[3][3];
#pragma unroll
    for (int f = 0; f < 3; ++f)
#pragma unroll
        for (int s = 0; s < 3; ++s)
            acc[f][s] = (f32x4){0.f, 0.f, 0.f, 0.f};

#pragma unroll
    for (int s = 0; s < 3; ++s) {
        const unsigned short* xrow = Xb + (long)(s * 16 + ml) * 192 + qk * 8;
#pragma unroll
        for (int kk = 0; kk < 6; ++kk) {
            bf16x8 bfr = *(const bf16x8*)(xrow + kk * 32);
#pragma unroll
            for (int f = 0; f < 3; ++f)
                acc[f][s] = __builtin_amdgcn_mfma_f32_16x16x32_bf16(afr[f][kk], bfr, acc[f][s], 0, 0, 0);
        }
    }

#pragma unroll
    for (int f = 0; f < 3; ++f) {
        if (OUTBF) {
            unsigned short* Out = (unsigned short*)Outv + (long)b * oBatchStride;
#pragma unroll
            for (int s = 0; s < 3; ++s) {
                const int gm = mbase + f * 16 + qk * 4;
                const int gn = n0 + s * 16 + ml;
#pragma unroll
                for (int i = 0; i < 4; ++i)
                    Out[(long)(gm + i) * HW + gn] = f2bf(acc[f][s][i]);
            }
        } else {
            float* Out = (float*)Outv + (long)b * oBatchStride;
#pragma unroll
            for (int s = 0; s < 3; ++s) {
                const int gm = mbase + f * 16 + qk * 4;
                const int gn = n0 + s * 16 + ml;
#pragma unroll
                for (int i = 0; i < 4; ++i)
                    Out[(long)(gm + i) * HW + gn] = acc[f][s][i];
            }
        }
    }
}

// ---------------------------------------------------------------------------
// Depthwise 3x3 conv (SAME, zero pad), LDS-free, int4-vectorized.
// Also accumulates per-channel sum-of-squares for q/k channels (ch < 384).
// ---------------------------------------------------------------------------
__global__ __launch_bounds__(256) void dwconv_kernel(
    const unsigned short* __restrict__ qkv,
    const float* __restrict__ wdw,
    unsigned short* __restrict__ dwout,
    float* __restrict__ ssq)
{
    const int ht = blockIdx.x;   // 0..23 (8-row tiles)
    const int ch = blockIdx.y;   // 0..575
    const int b  = blockIdx.z;
    const int tid = threadIdx.x;
    const int lane = tid & 63;
    const int h0 = ht * 8;
    const int t  = tid & 31;     // lane in row group; 0..23 active
    const int hh = tid >> 5;     // 0..7 output row within tile
    const bool active = (t < 24);

    const float* wp = wdw + ch * 9;
    const float w00 = wp[0], w01 = wp[1], w02 = wp[2];
    const float w10 = wp[3], w11 = wp[4], w12 = wp[5];
    const float w20 = wp[6], w21 = wp[7], w22 = wp[8];

    const long chbase = (long)(b * 576 + ch) * HW;

    float x[3][8];
#pragma unroll
    for (int dy = 0; dy < 3; ++dy) {
        const int hr = h0 + hh + dy - 1;
        int4 ld = make_int4(0, 0, 0, 0);
        if (active && hr >= 0 && hr < 192)
            ld = *(const int4*)(qkv + chbase + (long)hr * 192 + t * 8);
        const unsigned short* u = (const unsigned short*)&ld;
#pragma unroll
        for (int j = 0; j < 8; ++j) x[dy][j] = bf2f(u[j]);
    }

    float lft[3], rgt[3];
#pragma unroll
    for (int dy = 0; dy < 3; ++dy) {
        float l = __shfl(x[dy][7], lane - 1, 64);
        float r = __shfl(x[dy][0], lane + 1, 64);
        lft[dy] = (t == 0) ? 0.f : l;
        rgt[dy] = (t >= 23) ? 0.f : r;
    }

    float acc[8];
#pragma unroll
    for (int j = 0; j < 8; ++j) {
        float a0 = (j == 0) ? lft[0] : x[0][j - 1];
        float a2 = (j == 7) ? rgt[0] : x[0][j + 1];
        float b0 = (j == 0) ? lft[1] : x[1][j - 1];
        float b2 = (j == 7) ? rgt[1] : x[1][j + 1];
        float c0 = (j == 0) ? lft[2] : x[2][j - 1];
        float c2 = (j == 7) ? rgt[2] : x[2][j + 1];
        acc[j] = w00 * a0 + w01 * x[0][j] + w02 * a2
               + w10 * b0 + w11 * x[1][j] + w12 * b2
               + w20 * c0 + w21 * x[2][j] + w22 * c2;
    }

    if (active) {
        int4 st;
        unsigned short* u = (unsigned short*)&st;
#pragma unroll
        for (int j = 0; j < 8; ++j) u[j] = f2bf(acc[j]);
        *(int4*)(dwout + chbase + (long)(h0 + hh) * 192 + t * 8) = st;
    }

    if (ch < 384) {
        float mysq = 0.f;
        if (active) {
#pragma unroll
            for (int j = 0; j < 8; ++j) mysq += acc[j] * acc[j];
        }
#pragma unroll
        for (int off = 32; off > 0; off >>= 1) mysq += __shfl_xor(mysq, off, 64);
        __shared__ float red[4];
        if (lane == 0) red[tid >> 6] = mysq;
        __syncthreads();
        if (tid == 0) atomicAdd(&ssq[b * 384 + ch], red[0] + red[1] + red[2] + red[3]);
    }
}

// ---------------------------------------------------------------------------
// Gram: gram[b,h,d,e] += sum_n q[d][n]*k[e][n] over a 128-col chunk. MFMA TN.
// ---------------------------------------------------------------------------
__global__ __launch_bounds__(64) void gram_kernel(
    const unsigned short* __restrict__ dwb, float* __restrict__ gram)
{
    const int chunk = blockIdx.x;  // 0..287
    const int bh = blockIdx.y;     // 0..7
    const int b = bh >> 2, h = bh & 3;
    const int lane = threadIdx.x;
    const int row = lane & 15, qk = lane >> 4;
    const long n0 = (long)chunk * 128;

    const unsigned short* qb = dwb + (long)(b * 576 + h * 48) * HW + n0;
    const unsigned short* kb = dwb + (long)(b * 576 + 192 + h * 48) * HW + n0;

    f32x4 acc[3][3];
#pragma unroll
    for (int f = 0; f < 3; ++f)
#pragma unroll
        for (int g = 0; g < 3; ++g) acc[f][g] = (f32x4){0.f, 0.f, 0.f, 0.f};

#pragma unroll
    for (int kk = 0; kk < 128; kk += 32) {
        const int col = kk + qk * 8;
        bf16x8 aq[3], bk[3];
#pragma unroll
        for (int f = 0; f < 3; ++f) aq[f] = *(const bf16x8*)(qb + (long)(f * 16 + row) * HW + col);
#pragma unroll
        for (int g = 0; g < 3; ++g) bk[g] = *(const bf16x8*)(kb + (long)(g * 16 + row) * HW + col);
#pragma unroll
        for (int f = 0; f < 3; ++f)
#pragma unroll
            for (int g = 0; g < 3; ++g)
                acc[f][g] = __builtin_amdgcn_mfma_f32_16x16x32_bf16(aq[f], bk[g], acc[f][g], 0, 0, 0);
    }

    float* gb = gram + bh * 2304;
#pragma unroll
    for (int f = 0; f < 3; ++f)
#pragma unroll
        for (int g = 0; g < 3; ++g)
#pragma unroll
            for (int i = 0; i < 4; ++i)
                atomicAdd(&gb[(f * 16 + qk * 4 + i) * 48 + g * 16 + row], acc[f][g][i]);
}

// ---------------------------------------------------------------------------
// attn = softmax( gram / (|q_d||k_e|) * softplus(logT) + eps ) over e
// ---------------------------------------------------------------------------
__global__ __launch_bounds__(64) void attn_kernel(
    const float* __restrict__ gram, const float* __restrict__ ssq,
    const float* __restrict__ lt, float* __restrict__ attn)
{
    const int bh = blockIdx.x;
    const int b = bh >> 2, h = bh & 3;
    const int d = threadIdx.x;
    if (d >= 48) return;
    const float temp = log1pf(expf(lt[h])) + 1e-6f;
    const float invq = 1.f / fmaxf(sqrtf(ssq[b * 384 + h * 48 + d]), 1e-12f);
    float p[48];
    float mx = -1e30f;
#pragma unroll
    for (int e = 0; e < 48; ++e) {
        float invk = 1.f / fmaxf(sqrtf(ssq[b * 384 + 192 + h * 48 + e]), 1e-12f);
        float g = gram[bh * 2304 + d * 48 + e] * invq * invk * temp;
        p[e] = g;
        mx = fmaxf(mx, g);
    }
    float sum = 0.f;
#pragma unroll
    for (int e = 0; e < 48; ++e) { float x = expf(p[e] - mx); p[e] = x; sum += x; }
    const float inv = 1.f / sum;
#pragma unroll
    for (int e = 0; e < 48; ++e) attn[bh * 2304 + d * 48 + e] = p[e] * inv;
}

// ---------------------------------------------------------------------------
// M[b][o][h*48+e] = sum_d wproj[o][h*48+d] * attn[b][h][d][e]   (bf16 out)
// ---------------------------------------------------------------------------
__global__ __launch_bounds__(192) void mproj_kernel(
    const float* __restrict__ wproj, const float* __restrict__ attn,
    unsigned short* __restrict__ Mb)
{
    const int o = blockIdx.x;
    const int b = blockIdx.y;
    const int he = threadIdx.x;
    const int h = he / 48, e = he - h * 48;
    const float* ar = attn + ((b * 4 + h) * 48) * 48 + e;
    const float* wr = wproj + o * 192 + h * 48;
    float acc = 0.f;
#pragma unroll
    for (int d = 0; d < 48; ++d) acc += wr[d] * ar[d * 48];
    Mb[(long)(b * 192 + o) * 192 + he] = f2bf(acc);
}

__global__ void cvt_bf16_kernel(const float* __restrict__ in,
                                unsigned short* __restrict__ out, int n)
{
    int i = blockIdx.x * 256 + threadIdx.x;
    if (i < n) out[i] = f2bf(in[i]);
}

// ---------------------------------------------------------------------------
extern "C" void kernel_launch(void* const* d_in, const int* in_sizes, int n_in,
                              void* d_out, int out_size, void* d_ws, size_t ws_size,
                              hipStream_t stream)
{
    const float* x      = (const float*)d_in[0];
    const float* w_qkv  = (const float*)d_in[1];
    const float* w_dw   = (const float*)d_in[2];
    const float* w_proj = (const float*)d_in[3];
    const float* lt     = (const float*)d_in[4];

    char* ws = (char*)d_ws;
    unsigned short* wqkv_b = (unsigned short*)(ws + 0);          // 221184 B
    float* gram            = (float*)(ws + 221184);              // 73728 B
    float* ssq             = (float*)(ws + 294912);              // 3072 B
    float* attn            = (float*)(ws + 297984);              // 73728 B
    unsigned short* Mb     = (unsigned short*)(ws + 371712);     // 147456 B
    unsigned short* qkvb   = (unsigned short*)(ws + 524288);     // 84934656 B
    unsigned short* dwb    = (unsigned short*)(ws + 524288 + 84934656ll);
    // overlays (lifetime-disjoint):
    unsigned short* xT = dwb;    // 28311552 B; dead before dwconv writes dwb
    unsigned short* vT = qkvb;   // 28311552 B; qkvb dead after dwconv

    // zero the atomic accumulators (gram + ssq are adjacent)
    hipMemsetAsync(gram, 0, 73728 + 3072, stream);

    // w_qkv -> bf16
    cvt_bf16_kernel<<<dim3((110592 + 255) / 256), 256, 0, stream>>>(w_qkv, wqkv_b, 110592);

    // xT = transpose(x) -> bf16 [b][HW][192]
    xpose_kernel<true><<<dim3(576, 3, 2), 256, 0, stream>>>(
        (const void*)x, xT, (long)192 * HW);

    // qkv = w_qkv @ x via xT  (M=576, N=HW, K=192)
    gemm_nols<true><<<dim3(768, 2, 3), 256, 0, stream>>>(
        wqkv_b, xT, (void*)qkvb, 0L, (long)576 * HW);

    // depthwise 3x3 + sumsq(q,k)  (overwrites xT region with dwb)
    dwconv_kernel<<<dim3(24, 576, 2), 256, 0, stream>>>(qkvb, w_dw, dwb, ssq);

    // gram = q @ k^T per (b, head)
    gram_kernel<<<dim3(288, 8), 64, 0, stream>>>(dwb, gram);

    // vT = transpose(v) -> bf16 [b][HW][192]  (into qkvb region)
    xpose_kernel<false><<<dim3(576, 3, 2), 256, 0, stream>>>(
        (const void*)(dwb + (long)384 * HW), vT, (long)576 * HW);

    // softmax(normalized gram * temperature)
    attn_kernel<<<dim3(8), 64, 0, stream>>>(gram, ssq, lt, attn);

    // M = w_proj @ attn (per batch, per head), bf16
    mproj_kernel<<<dim3(192, 2), 192, 0, stream>>>(w_proj, attn, Mb);

    // out = M @ v via vT  (M=192, N=HW, K=192), fp32 out
    gemm_nols<false><<<dim3(768, 2, 1), 256, 0, stream>>>(
        Mb, vT, d_out, (long)192 * 192, (long)192 * HW);
}

// Round 6
// 314.971 us; speedup vs baseline: 1.1005x; 1.1005x over previous
//
#include <hip/hip_runtime.h>
#include <math.h>

#define HW 36864
#define CC 192

typedef __attribute__((ext_vector_type(4))) float f32x4;
typedef __attribute__((ext_vector_type(8))) short bf16x8;

__device__ __forceinline__ float bf2f(unsigned short u) {
    return __uint_as_float(((unsigned int)u) << 16);
}
__device__ __forceinline__ unsigned short f2bf(float f) {
    unsigned int u = __float_as_uint(f);
    unsigned int r = (u + 0x7fffu + ((u >> 16) & 1u)) >> 16;
    return (unsigned short)r;
}

// ---------------------------------------------------------------------------
// Tile transpose: src [b][192 ch][HW] (f32 or bf16) -> dst bf16 [b][HW][192].
// 64ch x 64n tiles through LDS. Grid: (HW/64, 3, batch), 256 threads.
// ---------------------------------------------------------------------------
template<bool INF32>
__global__ __launch_bounds__(256) void xpose_kernel(
    const void* __restrict__ src, unsigned short* __restrict__ dst,
    long srcBatchStride)
{
    const int n0  = blockIdx.x * 64;
    const int ch0 = blockIdx.y * 64;
    const int b   = blockIdx.z;
    const int tid = threadIdx.x;
    const int chp = tid >> 3;   // channel pair 0..31
    const int nq  = tid & 7;    // n-chunk of 8

    __shared__ unsigned int T[64 * 33];

    const long rbase = (long)b * srcBatchStride + (long)(ch0 + 2 * chp) * HW + n0 + nq * 8;
    unsigned int pk[8];
    if (INF32) {
        const float* s0 = (const float*)src + rbase;
        float4 a0 = *(const float4*)(s0);
        float4 a1 = *(const float4*)(s0 + 4);
        float4 b0 = *(const float4*)(s0 + HW);
        float4 b1 = *(const float4*)(s0 + HW + 4);
        float lo[8] = {a0.x, a0.y, a0.z, a0.w, a1.x, a1.y, a1.z, a1.w};
        float hi[8] = {b0.x, b0.y, b0.z, b0.w, b1.x, b1.y, b1.z, b1.w};
#pragma unroll
        for (int j = 0; j < 8; ++j)
            pk[j] = (unsigned int)f2bf(lo[j]) | ((unsigned int)f2bf(hi[j]) << 16);
    } else {
        const unsigned short* s0 = (const unsigned short*)src + rbase;
        int4 r0 = *(const int4*)(s0);
        int4 r1 = *(const int4*)(s0 + HW);
        const unsigned short* u0 = (const unsigned short*)&r0;
        const unsigned short* u1 = (const unsigned short*)&r1;
#pragma unroll
        for (int j = 0; j < 8; ++j)
            pk[j] = (unsigned int)u0[j] | ((unsigned int)u1[j] << 16);
    }
#pragma unroll
    for (int j = 0; j < 8; ++j)
        T[(nq * 8 + j) * 33 + chp] = pk[j];
    __syncthreads();

#pragma unroll
    for (int it = 0; it < 2; ++it) {
        const int slot = it * 256 + tid;
        const int n = slot >> 3, seg = slot & 7;
        uint4 v = *(const uint4*)&T[n * 33 + seg * 4];
        *(uint4*)(dst + ((long)b * HW + n0 + n) * 192 + ch0 + seg * 8) = v;
    }
}

// ---------------------------------------------------------------------------
// LDS-A streaming-B GEMM: Out[b][m][n] = sum_k A[b][m][k] * XT[b][n][k]
// A: bf16 [M][192] k-contig. 48-row m-tile staged to LDS once (19.2 KB,
// stride 200 shorts -> <=2-way conflicts). B-frags read directly from
// XT [HW][192] (16 full lines per instr, L2/L3-hot via m-fastest grid).
// Block = 48 m x 256 n (4 waves x 64 n). Per wave per k-step: 3 ds_read_b128
// + 4 global16B + 12 MFMA. Grid: (M/48, batch, HW/256) - m fastest.
// ---------------------------------------------------------------------------
template<bool OUTBF>
__global__ __launch_bounds__(256, 4) void gemm_ldsa(
    const unsigned short* __restrict__ A,
    const unsigned short* __restrict__ XT,
    void* __restrict__ Outv,
    long aBatchStride, long oBatchStride)
{
    const int mbase = blockIdx.x * 48;
    const int b     = blockIdx.y;
    const int n0    = blockIdx.z * 256;
    const int tid  = threadIdx.x;
    const int lane = tid & 63;
    const int wave = tid >> 6;
    const int ml = lane & 15, qk = lane >> 4;

    __shared__ __attribute__((aligned(16))) unsigned short As[48 * 200];

    // stage A-tile 48 x 192 (k-contig rows)
    const unsigned short* Ab = A + (long)b * aBatchStride;
    for (int idx = tid; idx < 1152; idx += 256) {
        const int row = idx / 24, c = idx - row * 24;
        *(int4*)&As[row * 200 + c * 8] = *(const int4*)(Ab + (long)(mbase + row) * 192 + c * 8);
    }
    __syncthreads();

    const unsigned short* Xb = XT + ((long)b * HW + n0 + wave * 64) * 192;

    f32x4 acc[3][4];  // [m-frag][n-frag]
#pragma unroll
    for (int f = 0; f < 3; ++f)
#pragma unroll
        for (int s = 0; s < 4; ++s)
            acc[f][s] = (f32x4){0.f, 0.f, 0.f, 0.f};

#pragma unroll
    for (int kk = 0; kk < 6; ++kk) {
        bf16x8 afr[3];
#pragma unroll
        for (int f = 0; f < 3; ++f)
            afr[f] = *(const bf16x8*)&As[(f * 16 + ml) * 200 + kk * 32 + qk * 8];
        bf16x8 bfr[4];
#pragma unroll
        for (int s = 0; s < 4; ++s)
            bfr[s] = *(const bf16x8*)(Xb + (long)(s * 16 + ml) * 192 + kk * 32 + qk * 8);
#pragma unroll
        for (int f = 0; f < 3; ++f)
#pragma unroll
            for (int s = 0; s < 4; ++s)
                acc[f][s] = __builtin_amdgcn_mfma_f32_16x16x32_bf16(afr[f], bfr[s], acc[f][s], 0, 0, 0);
    }

#pragma unroll
    for (int f = 0; f < 3; ++f) {
        if (OUTBF) {
            unsigned short* Out = (unsigned short*)Outv + (long)b * oBatchStride;
#pragma unroll
            for (int s = 0; s < 4; ++s) {
                const int gm = mbase + f * 16 + qk * 4;
                const int gn = n0 + wave * 64 + s * 16 + ml;
#pragma unroll
                for (int i = 0; i < 4; ++i)
                    Out[(long)(gm + i) * HW + gn] = f2bf(acc[f][s][i]);
            }
        } else {
            float* Out = (float*)Outv + (long)b * oBatchStride;
#pragma unroll
            for (int s = 0; s < 4; ++s) {
                const int gm = mbase + f * 16 + qk * 4;
                const int gn = n0 + wave * 64 + s * 16 + ml;
#pragma unroll
                for (int i = 0; i < 4; ++i)
                    Out[(long)(gm + i) * HW + gn] = acc[f][s][i];
            }
        }
    }
}

// ---------------------------------------------------------------------------
// Depthwise 3x3 conv (SAME, zero pad), LDS-free, int4-vectorized.
// Also accumulates per-channel sum-of-squares for q/k channels (ch < 384).
// ---------------------------------------------------------------------------
__global__ __launch_bounds__(256) void dwconv_kernel(
    const unsigned short* __restrict__ qkv,
    const float* __restrict__ wdw,
    unsigned short* __restrict__ dwout,
    float* __restrict__ ssq)
{
    const int ht = blockIdx.x;   // 0..23 (8-row tiles)
    const int ch = blockIdx.y;   // 0..575
    const int b  = blockIdx.z;
    const int tid = threadIdx.x;
    const int lane = tid & 63;
    const int h0 = ht * 8;
    const int t  = tid & 31;     // lane in row group; 0..23 active
    const int hh = tid >> 5;     // 0..7 output row within tile
    const bool active = (t < 24);

    const float* wp = wdw + ch * 9;
    const float w00 = wp[0], w01 = wp[1], w02 = wp[2];
    const float w10 = wp[3], w11 = wp[4], w12 = wp[5];
    const float w20 = wp[6], w21 = wp[7], w22 = wp[8];

    const long chbase = (long)(b * 576 + ch) * HW;

    float x[3][8];
#pragma unroll
    for (int dy = 0; dy < 3; ++dy) {
        const int hr = h0 + hh + dy - 1;
        int4 ld = make_int4(0, 0, 0, 0);
        if (active && hr >= 0 && hr < 192)
            ld = *(const int4*)(qkv + chbase + (long)hr * 192 + t * 8);
        const unsigned short* u = (const unsigned short*)&ld;
#pragma unroll
        for (int j = 0; j < 8; ++j) x[dy][j] = bf2f(u[j]);
    }

    float lft[3], rgt[3];
#pragma unroll
    for (int dy = 0; dy < 3; ++dy) {
        float l = __shfl(x[dy][7], lane - 1, 64);
        float r = __shfl(x[dy][0], lane + 1, 64);
        lft[dy] = (t == 0) ? 0.f : l;
        rgt[dy] = (t >= 23) ? 0.f : r;
    }

    float acc[8];
#pragma unroll
    for (int j = 0; j < 8; ++j) {
        float a0 = (j == 0) ? lft[0] : x[0][j - 1];
        float a2 = (j == 7) ? rgt[0] : x[0][j + 1];
        float b0 = (j == 0) ? lft[1] : x[1][j - 1];
        float b2 = (j == 7) ? rgt[1] : x[1][j + 1];
        float c0 = (j == 0) ? lft[2] : x[2][j - 1];
        float c2 = (j == 7) ? rgt[2] : x[2][j + 1];
        acc[j] = w00 * a0 + w01 * x[0][j] + w02 * a2
               + w10 * b0 + w11 * x[1][j] + w12 * b2
               + w20 * c0 + w21 * x[2][j] + w22 * c2;
    }

    if (active) {
        int4 st;
        unsigned short* u = (unsigned short*)&st;
#pragma unroll
        for (int j = 0; j < 8; ++j) u[j] = f2bf(acc[j]);
        *(int4*)(dwout + chbase + (long)(h0 + hh) * 192 + t * 8) = st;
    }

    if (ch < 384) {
        float mysq = 0.f;
        if (active) {
#pragma unroll
            for (int j = 0; j < 8; ++j) mysq += acc[j] * acc[j];
        }
#pragma unroll
        for (int off = 32; off > 0; off >>= 1) mysq += __shfl_xor(mysq, off, 64);
        __shared__ float red[4];
        if (lane == 0) red[tid >> 6] = mysq;
        __syncthreads();
        if (tid == 0) atomicAdd(&ssq[b * 384 + ch], red[0] + red[1] + red[2] + red[3]);
    }
}

// ---------------------------------------------------------------------------
// Gram: gram[b,h,d,e] += sum_n q[d][n]*k[e][n] over a 128-col chunk. MFMA TN.
// ---------------------------------------------------------------------------
__global__ __launch_bounds__(64) void gram_kernel(
    const unsigned short* __restrict__ dwb, float* __restrict__ gram)
{
    const int chunk = blockIdx.x;  // 0..287
    const int bh = blockIdx.y;     // 0..7
    const int b = bh >> 2, h = bh & 3;
    const int lane = threadIdx.x;
    const int row = lane & 15, qk = lane >> 4;
    const long n0 = (long)chunk * 128;

    const unsigned short* qb = dwb + (long)(b * 576 + h * 48) * HW + n0;
    const unsigned short* kb = dwb + (long)(b * 576 + 192 + h * 48) * HW + n0;

    f32x4 acc[3][3];
#pragma unroll
    for (int f = 0; f < 3; ++f)
#pragma unroll
        for (int g = 0; g < 3; ++g) acc[f][g] = (f32x4){0.f, 0.f, 0.f, 0.f};

#pragma unroll
    for (int kk = 0; kk < 128; kk += 32) {
        const int col = kk + qk * 8;
        bf16x8 aq[3], bk[3];
#pragma unroll
        for (int f = 0; f < 3; ++f) aq[f] = *(const bf16x8*)(qb + (long)(f * 16 + row) * HW + col);
#pragma unroll
        for (int g = 0; g < 3; ++g) bk[g] = *(const bf16x8*)(kb + (long)(g * 16 + row) * HW + col);
#pragma unroll
        for (int f = 0; f < 3; ++f)
#pragma unroll
            for (int g = 0; g < 3; ++g)
                acc[f][g] = __builtin_amdgcn_mfma_f32_16x16x32_bf16(aq[f], bk[g], acc[f][g], 0, 0, 0);
    }

    float* gb = gram + bh * 2304;
#pragma unroll
    for (int f = 0; f < 3; ++f)
#pragma unroll
        for (int g = 0; g < 3; ++g)
#pragma unroll
            for (int i = 0; i < 4; ++i)
                atomicAdd(&gb[(f * 16 + qk * 4 + i) * 48 + g * 16 + row], acc[f][g][i]);
}

// ---------------------------------------------------------------------------
// attn = softmax( gram / (|q_d||k_e|) * softplus(logT) + eps ) over e
// ---------------------------------------------------------------------------
__global__ __launch_bounds__(64) void attn_kernel(
    const float* __restrict__ gram, const float* __restrict__ ssq,
    const float* __restrict__ lt, float* __restrict__ attn)
{
    const int bh = blockIdx.x;
    const int b = bh >> 2, h = bh & 3;
    const int d = threadIdx.x;
    if (d >= 48) return;
    const float temp = log1pf(expf(lt[h])) + 1e-6f;
    const float invq = 1.f / fmaxf(sqrtf(ssq[b * 384 + h * 48 + d]), 1e-12f);
    float p[48];
    float mx = -1e30f;
#pragma unroll
    for (int e = 0; e < 48; ++e) {
        float invk = 1.f / fmaxf(sqrtf(ssq[b * 384 + 192 + h * 48 + e]), 1e-12f);
        float g = gram[bh * 2304 + d * 48 + e] * invq * invk * temp;
        p[e] = g;
        mx = fmaxf(mx, g);
    }
    float sum = 0.f;
#pragma unroll
    for (int e = 0; e < 48; ++e) { float x = expf(p[e] - mx); p[e] = x; sum += x; }
    const float inv = 1.f / sum;
#pragma unroll
    for (int e = 0; e < 48; ++e) attn[bh * 2304 + d * 48 + e] = p[e] * inv;
}

// ---------------------------------------------------------------------------
// M[b][o][h*48+e] = sum_d wproj[o][h*48+d] * attn[b][h][d][e]   (bf16 out)
// ---------------------------------------------------------------------------
__global__ __launch_bounds__(192) void mproj_kernel(
    const float* __restrict__ wproj, const float* __restrict__ attn,
    unsigned short* __restrict__ Mb)
{
    const int o = blockIdx.x;
    const int b = blockIdx.y;
    const int he = threadIdx.x;
    const int h = he / 48, e = he - h * 48;
    const float* ar = attn + ((b * 4 + h) * 48) * 48 + e;
    const float* wr = wproj + o * 192 + h * 48;
    float acc = 0.f;
#pragma unroll
    for (int d = 0; d < 48; ++d) acc += wr[d] * ar[d * 48];
    Mb[(long)(b * 192 + o) * 192 + he] = f2bf(acc);
}

__global__ void cvt_bf16_kernel(const float* __restrict__ in,
                                unsigned short* __restrict__ out, int n)
{
    int i = blockIdx.x * 256 + threadIdx.x;
    if (i < n) out[i] = f2bf(in[i]);
}

// ---------------------------------------------------------------------------
extern "C" void kernel_launch(void* const* d_in, const int* in_sizes, int n_in,
                              void* d_out, int out_size, void* d_ws, size_t ws_size,
                              hipStream_t stream)
{
    const float* x      = (const float*)d_in[0];
    const float* w_qkv  = (const float*)d_in[1];
    const float* w_dw   = (const float*)d_in[2];
    const float* w_proj = (const float*)d_in[3];
    const float* lt     = (const float*)d_in[4];

    char* ws = (char*)d_ws;
    unsigned short* wqkv_b = (unsigned short*)(ws + 0);          // 221184 B
    float* gram            = (float*)(ws + 221184);              // 73728 B
    float* ssq             = (float*)(ws + 294912);              // 3072 B
    float* attn            = (float*)(ws + 297984);              // 73728 B
    unsigned short* Mb     = (unsigned short*)(ws + 371712);     // 147456 B
    unsigned short* qkvb   = (unsigned short*)(ws + 524288);     // 84934656 B
    unsigned short* dwb    = (unsigned short*)(ws + 524288 + 84934656ll);
    // overlays (lifetime-disjoint):
    unsigned short* xT = dwb;    // 28311552 B; dead before dwconv writes dwb
    unsigned short* vT = qkvb;   // 28311552 B; qkvb dead after dwconv

    // zero the atomic accumulators (gram + ssq are adjacent)
    hipMemsetAsync(gram, 0, 73728 + 3072, stream);

    // w_qkv -> bf16
    cvt_bf16_kernel<<<dim3((110592 + 255) / 256), 256, 0, stream>>>(w_qkv, wqkv_b, 110592);

    // xT = transpose(x) -> bf16 [b][HW][192]
    xpose_kernel<true><<<dim3(576, 3, 2), 256, 0, stream>>>(
        (const void*)x, xT, (long)192 * HW);

    // qkv = w_qkv @ x via xT  (M=576, N=HW, K=192); m fastest for L2 reuse
    gemm_ldsa<true><<<dim3(12, 2, 144), 256, 0, stream>>>(
        wqkv_b, xT, (void*)qkvb, 0L, (long)576 * HW);

    // depthwise 3x3 + sumsq(q,k)  (overwrites xT region with dwb)
    dwconv_kernel<<<dim3(24, 576, 2), 256, 0, stream>>>(qkvb, w_dw, dwb, ssq);

    // gram = q @ k^T per (b, head)
    gram_kernel<<<dim3(288, 8), 64, 0, stream>>>(dwb, gram);

    // vT = transpose(v) -> bf16 [b][HW][192]  (into qkvb region)
    xpose_kernel<false><<<dim3(576, 3, 2), 256, 0, stream>>>(
        (const void*)(dwb + (long)384 * HW), vT, (long)576 * HW);

    // softmax(normalized gram * temperature)
    attn_kernel<<<dim3(8), 64, 0, stream>>>(gram, ssq, lt, attn);

    // M = w_proj @ attn (per batch, per head), bf16
    mproj_kernel<<<dim3(192, 2), 192, 0, stream>>>(w_proj, attn, Mb);

    // out = M @ v via vT  (M=192, N=HW, K=192), fp32 out
    gemm_ldsa<false><<<dim3(4, 2, 144), 256, 0, stream>>>(
        Mb, vT, d_out, (long)192 * 192, (long)192 * HW);
}